// Round 10
// baseline (100.878 us; speedup 1.0000x reference)
//
#include <hip/hip_runtime.h>

#define EPSF 1e-12f

#define B_SZ 256
#define DIN 512
#define DOUT 512
#define KN 16
#define NSEG 15

#define O_TILE 16                 // R8: 32->16. LDS 68->34 KB -> 4 blocks/CU (16 waves/CU).
#define I_CHUNK 16
#define N_CHUNK (DIN / I_CHUNK)   // 32 i-chunks -> 32 partials
#define N_OT (DOUT / O_TILE)      // 32 o-tiles

#define ROW_SLOTS 17              // 15 used + 2 pad -> 136 B rows

// f16x2 pack/unpack helpers (table is f16; weights/accum stay f32)
union H2U { _Float16 h[2]; unsigned u; };
__device__ __forceinline__ unsigned packh2(float a, float b) {
  H2U v; v.h[0] = (_Float16)a; v.h[1] = (_Float16)b; return v.u;
}
__device__ __forceinline__ float loh(unsigned u) { H2U v; v.u = u; return (float)v.h[0]; }
__device__ __forceinline__ float hih(unsigned u) { H2U v; v.u = u; return (float)v.h[1]; }

// ---------------------------------------------------------------------------
// Main kernel. Grid 1024 = 32 o-tiles x 32 i-chunks, 256 threads = all b.
// Phase A: f16 (C_k,S_k,C_k+1,S_k+1) quad-slot table in LDS (fused PCHIP).
// Phase B: lane = b; one ds_read_b64 + 4 cvt + 4 fma per (b,i,o) item.
// R3 lesson: il loop MUST NOT unroll (spill -> 600MB scratch). unroll 1 pins.
// R7 lesson: f32->f16 table only bought 4us => not LDS-BW-bound; 2 waves/SIMD
// (23% occ) latency-bound. This round: O_TILE 16 -> 4 blocks/CU, 2x waves.
// ---------------------------------------------------------------------------
__global__ __launch_bounds__(256, 4) void kan_main(
    const float* __restrict__ x, const float* __restrict__ coeffs,
    const float* __restrict__ knots, float* __restrict__ part) {
  __shared__ uint2 tbl[O_TILE * I_CHUNK * ROW_SLOTS];   // 256 rows * 136 B = 34 KB
  int bid = blockIdx.x;
  int c  = bid >> 5;           // i-chunk 0..31
  int ot = bid & 31;           // o-tile  0..31
  int i0 = c * I_CHUNK;
  int o0 = ot * O_TILE;
  int t = threadIdx.x;

  // knot-derived constants (uniform)
  float kn[KN];
#pragma unroll
  for (int j = 0; j < 4; ++j) {
    float4 kk = reinterpret_cast<const float4*>(knots)[j];
    kn[4 * j + 0] = kk.x; kn[4 * j + 1] = kk.y;
    kn[4 * j + 2] = kk.z; kn[4 * j + 3] = kk.w;
  }
  float h[NSEG];
#pragma unroll
  for (int j = 0; j < NSEG; ++j) h[j] = kn[j + 1] - kn[j];
  float x0 = kn[0], xN = kn[KN - 1];
  float dx = (xN - x0) / (float)(KN - 1);

  // ---- Phase A: 256 rows / 256 threads = 1 row each ----
  {
    int r  = t;                // row = ol*16 + il
    int il = r & 15;
    int ol = r >> 4;           // 0..15
    const float* crow = coeffs + ((size_t)(o0 + ol) * DIN + (i0 + il)) * KN;
    float C[KN];
#pragma unroll
    for (int j = 0; j < 4; ++j) {
      float4 v = reinterpret_cast<const float4*>(crow)[j];
      C[4 * j + 0] = v.x; C[4 * j + 1] = v.y;
      C[4 * j + 2] = v.z; C[4 * j + 3] = v.w;
    }
    float del[NSEG];
#pragma unroll
    for (int j = 0; j < NSEG; ++j) del[j] = (C[j + 1] - C[j]) / (h[j] + EPSF);
    float d[KN];
    {
      float d0 = ((2.f * h[0] + h[1]) * del[0] - h[0] * del[1]) / (h[0] + h[1] + EPSF);
      if (d0 * del[0] <= 0.f) d0 = 0.f;
      else if (del[0] * del[1] < 0.f && fabsf(d0) > 3.f * fabsf(del[0])) d0 = 3.f * del[0];
      d[0] = d0;
      float dn = ((2.f * h[14] + h[13]) * del[14] - h[14] * del[13]) / (h[14] + h[13] + EPSF);
      if (dn * del[14] <= 0.f) dn = 0.f;
      else if (del[14] * del[13] < 0.f && fabsf(dn) > 3.f * fabsf(del[14])) dn = 3.f * del[14];
      d[15] = dn;
    }
#pragma unroll
    for (int j = 1; j <= 14; ++j) {
      float del0 = del[j - 1], del1 = del[j];
      float w1 = 2.f * h[j] + h[j - 1];
      float w2 = h[j] + 2.f * h[j - 1];
      float e0 = del0 + EPSF, e1 = del1 + EPSF;
      float prod = e0 * e1;
      float dj = (w1 + w2) * prod / (w1 * e1 + w2 * e0 + EPSF * prod);
      d[j] = (del0 * del1 > 0.f) ? dj : 0.f;
    }
    uint2* rowp = &tbl[r * ROW_SLOTS];
#pragma unroll
    for (int k = 0; k < NSEG; ++k)
      rowp[k] = make_uint2(packh2(C[k], d[k]), packh2(C[k + 1], d[k + 1]));
  }
  __syncthreads();

  // ---- Phase B ----
  float acc[O_TILE];
#pragma unroll
  for (int o = 0; o < O_TILE; ++o) acc[o] = 0.f;
  int b = t;
  const float* xrow = x + (size_t)b * DIN + i0;   // one 64B line per thread
#pragma unroll 1   // DO NOT unroll: full unroll spills acc[] (R3: 348us, 600MB scratch)
  for (int il = 0; il < I_CHUNK; ++il) {
    float xv = xrow[il];
    float wx, wy, wz, ww;
    int kk;
    if (xv < x0) {                 // left linear extrapolation (slot 0)
      wx = 1.f; wy = xv - x0; wz = 0.f; ww = 0.f; kk = 0;
    } else if (xv > xN) {          // right linear extrapolation (slot 14)
      wx = 0.f; wy = 0.f; wz = 1.f; ww = xv - xN; kk = NSEG - 1;
    } else {
      float u = (xv - x0) / (dx + EPSF);
      kk = (int)u;                 // u >= 0 here, floor == trunc
      if (kk > NSEG - 1) kk = NSEG - 1;
      float tt = u - (float)kk;
      float t2 = tt * tt, t3 = t2 * tt;
      wx = 2.f * t3 - 3.f * t2 + 1.f;
      wy = dx * (t3 - 2.f * t2 + tt);
      wz = -2.f * t3 + 3.f * t2;
      ww = dx * (t3 - t2);
    }
    const uint2* bp = &tbl[il * ROW_SLOTS + kk];
#pragma unroll
    for (int ol = 0; ol < O_TILE; ++ol) {
      uint2 q = bp[ol * (ROW_SLOTS * I_CHUNK)];   // +2176 B per ol, max 32752 (imm-folds)
      acc[ol] = fmaf(wx, loh(q.x),
                fmaf(wy, hih(q.x),
                fmaf(wz, loh(q.y),
                fmaf(ww, hih(q.y), acc[ol]))));
    }
  }
  // partials [c][o][b] -> coalesced stores
#pragma unroll
  for (int ol = 0; ol < O_TILE; ++ol)
    part[((size_t)c * DOUT + (o0 + ol)) * B_SZ + b] = acc[ol];
}

// ---------------------------------------------------------------------------
// Reduce: 32 partials + bias. float4 over b: coalesced 16B/lane reads.
// ---------------------------------------------------------------------------
__global__ __launch_bounds__(256) void kan_reduce(
    const float4* __restrict__ part4, const float* __restrict__ bias,
    float* __restrict__ out) {
  int flat = blockIdx.x * 256 + threadIdx.x;   // 0..32767
  int bg = flat & 63;                          // b-group (4 consecutive b)
  int o  = flat >> 6;
  float4 a = make_float4(0.f, 0.f, 0.f, 0.f);
#pragma unroll 8
  for (int c = 0; c < N_CHUNK; ++c) {
    float4 p = part4[((size_t)c * DOUT + o) * (B_SZ / 4) + bg];
    a.x += p.x; a.y += p.y; a.z += p.z; a.w += p.w;
  }
  float bb = bias[o];
  int b0 = bg * 4;
  out[(size_t)(b0 + 0) * DOUT + o] = a.x + bb;
  out[(size_t)(b0 + 1) * DOUT + o] = a.y + bb;
  out[(size_t)(b0 + 2) * DOUT + o] = a.z + bb;
  out[(size_t)(b0 + 3) * DOUT + o] = a.w + bb;
}

extern "C" void kernel_launch(void* const* d_in, const int* in_sizes, int n_in,
                              void* d_out, int out_size, void* d_ws, size_t ws_size,
                              hipStream_t stream) {
  const float* x      = (const float*)d_in[0];
  const float* knots  = (const float*)d_in[1];
  const float* coeffs = (const float*)d_in[2];
  const float* bias   = (const float*)d_in[3];
  float* out = (float*)d_out;

  float* part = (float*)d_ws;   // 32*512*256*4 = 16 MB

  kan_main  <<<N_CHUNK * N_OT, 256, 0, stream>>>(x, coeffs, knots, part);
  kan_reduce<<<128, 256, 0, stream>>>((const float4*)part, bias, out);
}

// Round 12
// 92.302 us; speedup vs baseline: 1.0929x; 1.0929x over previous
//
#include <hip/hip_runtime.h>

#define EPSF 1e-12f

#define B_SZ 256
#define DIN 512
#define DOUT 512
#define KN 16
#define NSEG 15

#define O_TILE 16                 // 34 KB LDS -> 4 blocks/CU
#define I_CHUNK 16
#define N_CHUNK (DIN / I_CHUNK)   // 32 i-chunks
#define N_OT (DOUT / O_TILE)      // 32 o-tiles

#define ROW_SLOTS 17              // 15 used + 2 pad -> 136 B rows
#define OL_STRIDE_B (ROW_SLOTS * I_CHUNK * 8)   // 2176 B per ol (imm-folds)

typedef _Float16 h2v __attribute__((ext_vector_type(2)));
union H2U { _Float16 h[2]; h2v v; unsigned u; };
__device__ __forceinline__ unsigned packh2(float a, float b) {
  H2U t; t.h[0] = (_Float16)a; t.h[1] = (_Float16)b; return t.u;
}
__device__ __forceinline__ float loh(unsigned u) { H2U v; v.u = u; return (float)v.h[0]; }
__device__ __forceinline__ float hih(unsigned u) { H2U v; v.u = u; return (float)v.h[1]; }

// dot2: acc += a.lo*b.lo + a.hi*b.hi  (f16 inputs, f32 accumulate)
__device__ __forceinline__ float dot2(unsigned a, unsigned b, float acc) {
#if __has_builtin(__builtin_amdgcn_fdot2)
  H2U ua, ub; ua.u = a; ub.u = b;
  return __builtin_amdgcn_fdot2(ua.v, ub.v, acc, false);
#else
  return fmaf(loh(a), loh(b), fmaf(hih(a), hih(b), acc));
#endif
}

// ---------------------------------------------------------------------------
// Main kernel. Grid 1024 = 32 o-tiles x 32 i-chunks, 256 threads = all b.
// Phase A: f16 (C_k,S_k,C_k+1,S_k+1) quad-slot LDS table (fused PCHIP).
// Phase B (R11 rewrite): outer g=0..3 rolled; per group: one float4 x-load,
//   4 il weight-sets as NAMED regs (f16-packed), then 64 independent
//   {ds_read_b64 + 2 v_dot2_f32_f16}. Theory: R10 null (occupancy 2x -> no
//   change) => intra-wave serial chains bind; this breaks them + 4x less VALU.
// R3 lesson: NEVER fully unroll il against 16 ol (acc spill -> 600MB scratch).
// ---------------------------------------------------------------------------
__global__ __launch_bounds__(256, 4) void kan_main(
    const float* __restrict__ x, const float* __restrict__ coeffs,
    const float* __restrict__ knots, float* __restrict__ part) {
  __shared__ uint2 tbl[O_TILE * I_CHUNK * ROW_SLOTS];   // 256 rows * 136 B = 34 KB
  int bid = blockIdx.x;
  int c  = bid >> 5;           // i-chunk 0..31
  int ot = bid & 31;           // o-tile  0..31
  int i0 = c * I_CHUNK;
  int o0 = ot * O_TILE;
  int t = threadIdx.x;

  // knot-derived constants (uniform)
  float kn[KN];
#pragma unroll
  for (int j = 0; j < 4; ++j) {
    float4 kk = reinterpret_cast<const float4*>(knots)[j];
    kn[4 * j + 0] = kk.x; kn[4 * j + 1] = kk.y;
    kn[4 * j + 2] = kk.z; kn[4 * j + 3] = kk.w;
  }
  float h[NSEG];
#pragma unroll
  for (int j = 0; j < NSEG; ++j) h[j] = kn[j + 1] - kn[j];
  float x0 = kn[0], xN = kn[KN - 1];
  float dx = (xN - x0) / (float)(KN - 1);

  // ---- Phase A: 256 rows / 256 threads = 1 row each ----
  {
    int r  = t;                // row = ol*16 + il
    int il = r & 15;
    int ol = r >> 4;           // 0..15
    const float* crow = coeffs + ((size_t)(o0 + ol) * DIN + (i0 + il)) * KN;
    float C[KN];
#pragma unroll
    for (int j = 0; j < 4; ++j) {
      float4 v = reinterpret_cast<const float4*>(crow)[j];
      C[4 * j + 0] = v.x; C[4 * j + 1] = v.y;
      C[4 * j + 2] = v.z; C[4 * j + 3] = v.w;
    }
    float del[NSEG];
#pragma unroll
    for (int j = 0; j < NSEG; ++j) del[j] = (C[j + 1] - C[j]) / (h[j] + EPSF);
    float d[KN];
    {
      float d0 = ((2.f * h[0] + h[1]) * del[0] - h[0] * del[1]) / (h[0] + h[1] + EPSF);
      if (d0 * del[0] <= 0.f) d0 = 0.f;
      else if (del[0] * del[1] < 0.f && fabsf(d0) > 3.f * fabsf(del[0])) d0 = 3.f * del[0];
      d[0] = d0;
      float dn = ((2.f * h[14] + h[13]) * del[14] - h[14] * del[13]) / (h[14] + h[13] + EPSF);
      if (dn * del[14] <= 0.f) dn = 0.f;
      else if (del[14] * del[13] < 0.f && fabsf(dn) > 3.f * fabsf(del[14])) dn = 3.f * del[14];
      d[15] = dn;
    }
#pragma unroll
    for (int j = 1; j <= 14; ++j) {
      float del0 = del[j - 1], del1 = del[j];
      float w1 = 2.f * h[j] + h[j - 1];
      float w2 = h[j] + 2.f * h[j - 1];
      float e0 = del0 + EPSF, e1 = del1 + EPSF;
      float prod = e0 * e1;
      float dj = (w1 + w2) * prod / (w1 * e1 + w2 * e0 + EPSF * prod);
      d[j] = (del0 * del1 > 0.f) ? dj : 0.f;
    }
    uint2* rowp = &tbl[r * ROW_SLOTS];
#pragma unroll
    for (int k = 0; k < NSEG; ++k)
      rowp[k] = make_uint2(packh2(C[k], d[k]), packh2(C[k + 1], d[k + 1]));
  }
  __syncthreads();

  // ---- Phase B ----
  float acc[O_TILE];
#pragma unroll
  for (int o = 0; o < O_TILE; ++o) acc[o] = 0.f;
  int b = t;
  const float4* xr4 = reinterpret_cast<const float4*>(x + (size_t)b * DIN + i0);
  const char* tb = reinterpret_cast<const char*>(tbl);

#pragma unroll 1   // outer stays rolled (R3: full unroll => spill catastrophe)
  for (int g = 0; g < 4; ++g) {
    float4 xv4 = xr4[g];                       // one 16B load per 4 il's
    float xs0 = xv4.x, xs1 = xv4.y, xs2 = xv4.z, xs3 = xv4.w;
    unsigned wA[4], wB[4];
    int boff[4];
#pragma unroll
    for (int s = 0; s < 4; ++s) {              // fully unrolled: named regs only
      float xv = (s == 0) ? xs0 : (s == 1) ? xs1 : (s == 2) ? xs2 : xs3;
      float wx, wy, wz, ww;
      int kk;
      if (xv < x0) {                 // left linear extrapolation (slot 0)
        wx = 1.f; wy = xv - x0; wz = 0.f; ww = 0.f; kk = 0;
      } else if (xv > xN) {          // right linear extrapolation (slot 14)
        wx = 0.f; wy = 0.f; wz = 1.f; ww = xv - xN; kk = NSEG - 1;
      } else {
        float u = (xv - x0) / (dx + EPSF);
        kk = (int)u;                 // u >= 0, floor == trunc
        if (kk > NSEG - 1) kk = NSEG - 1;
        float tt = u - (float)kk;
        float t2 = tt * tt, t3 = t2 * tt;
        wx = 2.f * t3 - 3.f * t2 + 1.f;
        wy = dx * (t3 - 2.f * t2 + tt);
        wz = -2.f * t3 + 3.f * t2;
        ww = dx * (t3 - t2);
      }
      wA[s] = packh2(wx, wy);        // f16 weights: adds <=5e-6 abs error
      wB[s] = packh2(wz, ww);
      boff[s] = ((g * 4 + s) * ROW_SLOTS + kk) * 8;
    }
    // 64 independent gather+dot ops per group: deep ILP, short chains
#pragma unroll
    for (int s = 0; s < 4; ++s) {
#pragma unroll
      for (int ol = 0; ol < O_TILE; ++ol) {
        uint2 q = *reinterpret_cast<const uint2*>(tb + boff[s] + ol * OL_STRIDE_B);
        float a0 = dot2(q.x, wA[s], acc[ol]);
        acc[ol] = dot2(q.y, wB[s], a0);
      }
    }
  }
  // partials [c][o][b] -> coalesced stores
#pragma unroll
  for (int ol = 0; ol < O_TILE; ++ol)
    part[((size_t)c * DOUT + (o0 + ol)) * B_SZ + b] = acc[ol];
}

// ---------------------------------------------------------------------------
// Reduce: 32 partials + bias. float4 over b: coalesced 16B/lane reads.
// ---------------------------------------------------------------------------
__global__ __launch_bounds__(256) void kan_reduce(
    const float4* __restrict__ part4, const float* __restrict__ bias,
    float* __restrict__ out) {
  int flat = blockIdx.x * 256 + threadIdx.x;   // 0..32767
  int bg = flat & 63;                          // b-group (4 consecutive b)
  int o  = flat >> 6;
  float4 a = make_float4(0.f, 0.f, 0.f, 0.f);
#pragma unroll 8
  for (int c = 0; c < N_CHUNK; ++c) {
    float4 p = part4[((size_t)c * DOUT + o) * (B_SZ / 4) + bg];
    a.x += p.x; a.y += p.y; a.z += p.z; a.w += p.w;
  }
  float bb = bias[o];
  int b0 = bg * 4;
  out[(size_t)(b0 + 0) * DOUT + o] = a.x + bb;
  out[(size_t)(b0 + 1) * DOUT + o] = a.y + bb;
  out[(size_t)(b0 + 2) * DOUT + o] = a.z + bb;
  out[(size_t)(b0 + 3) * DOUT + o] = a.w + bb;
}

extern "C" void kernel_launch(void* const* d_in, const int* in_sizes, int n_in,
                              void* d_out, int out_size, void* d_ws, size_t ws_size,
                              hipStream_t stream) {
  const float* x      = (const float*)d_in[0];
  const float* knots  = (const float*)d_in[1];
  const float* coeffs = (const float*)d_in[2];
  const float* bias   = (const float*)d_in[3];
  float* out = (float*)d_out;

  float* part = (float*)d_ws;   // 32*512*256*4 = 16 MB

  kan_main  <<<N_CHUNK * N_OT, 256, 0, stream>>>(x, coeffs, knots, part);
  kan_reduce<<<128, 256, 0, stream>>>((const float4*)part, bias, out);
}